// Round 9
// baseline (621.613 us; speedup 1.0000x reference)
//
#include <hip/hip_runtime.h>
#include <stdint.h>

typedef float f32x4 __attribute__((ext_vector_type(4)));
typedef float f32x2 __attribute__((ext_vector_type(2)));
typedef short s16x8 __attribute__((ext_vector_type(8)));
typedef short s16x4 __attribute__((ext_vector_type(4)));

__device__ __forceinline__ unsigned short f2bf(float f) {
    uint32_t u = __float_as_uint(f);
    u += 0x7FFFu + ((u >> 16) & 1u);   // round-to-nearest-even
    return (unsigned short)(u >> 16);
}

// async 16B/lane global->LDS (wave-uniform LDS base + lane*16, per-lane gaddr)
__device__ __forceinline__ void g2l16(const short* g, short* l) {
    __builtin_amdgcn_global_load_lds(
        (const __attribute__((address_space(1))) uint32_t*)g,
        (__attribute__((address_space(3))) uint32_t*)l, 16, 0, 0);
}

// ---------- prep: normalize mem rows, emit MFMA-fragment-packed bf16 ----------
// packed piece (ct16,kb): 512 shorts at (ct16*(C/32)+kb)*512;
// short lane*8+j = B[col=ct16*16+(lane&15)][k=kb*32+(lane>>4)*8+j]
template<int C>
__device__ __forceinline__ void prep_body(const float* __restrict__ mp,
                                          short* __restrict__ nmp,
                                          int ct, short* stage) {
    const int tid = threadIdx.x;       // 256 threads
    const int row = tid >> 4;          // 0..15 (B column)
    const int c4  = tid & 15;
    constexpr int IT = C / 64;
    const f32x4* src = (const f32x4*)(mp + (size_t)(ct * 16 + row) * C);
    f32x4 vals[IT];
    float ss = 0.f;
#pragma unroll
    for (int i = 0; i < IT; ++i) {
        f32x4 v = src[c4 + 16 * i];
        vals[i] = v;
        ss += v.x * v.x + v.y * v.y + v.z * v.z + v.w * v.w;
    }
#pragma unroll
    for (int m = 1; m < 16; m <<= 1) ss += __shfl_xor(ss, m);
    const float inv = 1.f / fmaxf(sqrtf(ss), 1e-12f);
#pragma unroll
    for (int i = 0; i < IT; ++i) {
        f32x4 v = vals[i];
        s16x4 o;
        o[0] = (short)f2bf(v.x * inv);
        o[1] = (short)f2bf(v.y * inv);
        o[2] = (short)f2bf(v.z * inv);
        o[3] = (short)f2bf(v.w * inv);
        *(s16x4*)&stage[row * C + (c4 + 16 * i) * 4] = o;
    }
    __syncthreads();
    const int lane = tid & 63;
    const int wv = tid >> 6;
    constexpr int NKB = C / 32;
#pragma unroll
    for (int j = 0; j < NKB / 4; ++j) {
        const int kb = j * 4 + wv;
        const s16x8 v = *(const s16x8*)&stage[(lane & 15) * C + kb * 32 + (lane >> 4) * 8];
        *(s16x8*)&nmp[((size_t)ct * NKB + kb) * 512 + lane * 8] = v;
    }
}

__global__ __launch_bounds__(256) void prep_all(const float* m0, short* n0,
                                                const float* m1, short* n1,
                                                const float* m2, short* n2) {
    __shared__ short stage[16 * 1024];
    const int bid = blockIdx.x;
    if (bid < 64) prep_body<256>(m0, n0, bid, stage);
    else if (bid < 128) prep_body<512>(m1, n1, bid - 64, stage);
    else prep_body<1024>(m2, n2, bid - 128, stage);
}

// ---------- fused unit: BM=64 x BN=1024, LDS-staged B (gload_lds) + fused A copy ----------
template<int C>
__device__ __forceinline__ void unit_body(const float* __restrict__ feat,
                                          const float* __restrict__ memv,
                                          const short* __restrict__ nm,
                                          float* __restrict__ out_cat,
                                          float* __restrict__ out_w,
                                          int tile,
                                          short* Bs0, short* Bs1,
                                          short* As0, short* As1,
                                          float* invL, int* rowflag, int* anyflag) {
    constexpr int NKB = C / 32;          // K-chunks of 32
    const int tid  = threadIdx.x;        // 0..1023
    const int w    = tid >> 6;           // wave 0..15
    const int lane = tid & 63;
    const int g    = lane >> 4;
    const int ml   = lane & 15;
    const int row0 = tile * 64;

    if (tid == 0) *anyflag = 0;

    // staging roles: thread -> (row, float2-slot)
    const int srow = tid >> 4;           // 0..63
    const int skk  = tid & 15;           // float2 index within 32-float chunk
    const float* fsrc = feat + (size_t)(row0 + srow) * C + 2 * skk;
    float* fcpy = out_cat + (size_t)(row0 + srow) * (2 * C) + C + 2 * skk;
    // A-frag LDS offset (shorts): frag(srow>>4), ((g)*16+ml)*8+j with k=2*skk
    const int aoff = (srow >> 4) * 512 + ((skk >> 2) * 16 + (srow & 15)) * 8 + ((2 * skk) & 7);
    // B staging: wave w copies pieces ct = w*4..w*4+3
    const short* nsrc = nm + ((size_t)(w * 4) * NKB) * 512 + lane * 8;
    const int boff = (w * 4) * 512;      // LDS piece base (shorts)

    f32x4 acc[4][4];
#pragma unroll
    for (int rt = 0; rt < 4; ++rt)
#pragma unroll
        for (int ct = 0; ct < 4; ++ct)
            acc[rt][ct] = (f32x4){0.f, 0.f, 0.f, 0.f};

    float ss = 0.f;

    // ---- prologue: stage chunk 0 into buf0 ----
#pragma unroll
    for (int p = 0; p < 4; ++p)
        g2l16(nsrc + (size_t)p * NKB * 512, Bs0 + boff + p * 512);
    {
        f32x2 av = __builtin_nontemporal_load((const f32x2*)fsrc);
        __builtin_nontemporal_store(av, (f32x2*)fcpy);
        ss += av.x * av.x + av.y * av.y;
        const uint32_t pk = (uint32_t)f2bf(av.x) | ((uint32_t)f2bf(av.y) << 16);
        *(uint32_t*)&As0[aoff] = pk;
    }
    asm volatile("s_waitcnt vmcnt(0) lgkmcnt(0)" ::: "memory");
    __builtin_amdgcn_s_barrier();
    asm volatile("" ::: "memory");

    // ---- K loop: chunk ck lives in buf[ck&1] ----
    for (int ck = 0; ck < NKB; ++ck) {
        const int cur = ck & 1;
        const short* Bc = cur ? Bs1 : Bs0;
        const short* Ac = cur ? As1 : As0;
        short* Bn = cur ? Bs0 : Bs1;
        short* An = cur ? As0 : As1;
        const bool more = (ck + 1 < NKB);
        f32x2 av;
        if (more) {
#pragma unroll
            for (int p = 0; p < 4; ++p)
                g2l16(nsrc + ((size_t)p * NKB + (ck + 1)) * 512, Bn + boff + p * 512);
            av = __builtin_nontemporal_load((const f32x2*)(fsrc + (size_t)(ck + 1) * 32));
        }
        // GEMM on current chunk (LDS reads, linear -> conflict-free)
        s16x8 a[4], b[4];
#pragma unroll
        for (int rt = 0; rt < 4; ++rt)
            a[rt] = *(const s16x8*)&Ac[rt * 512 + lane * 8];
#pragma unroll
        for (int p = 0; p < 4; ++p)
            b[p] = *(const s16x8*)&Bc[boff + p * 512 + lane * 8];
#pragma unroll
        for (int rt = 0; rt < 4; ++rt)
#pragma unroll
            for (int ct = 0; ct < 4; ++ct)
                acc[rt][ct] = __builtin_amdgcn_mfma_f32_16x16x32_bf16(a[rt], b[ct], acc[rt][ct], 0, 0, 0);
        if (more) {
            __builtin_nontemporal_store(av, (f32x2*)(fcpy + (size_t)(ck + 1) * 32));
            ss += av.x * av.x + av.y * av.y;
            const uint32_t pk = (uint32_t)f2bf(av.x) | ((uint32_t)f2bf(av.y) << 16);
            *(uint32_t*)&An[aoff] = pk;
        }
        asm volatile("s_waitcnt vmcnt(0) lgkmcnt(0)" ::: "memory");
        __builtin_amdgcn_s_barrier();
        asm volatile("" ::: "memory");
    }

    // ---- invn: reduce sumsq over the 16 staging lanes of each row ----
#pragma unroll
    for (int m = 1; m < 16; m <<= 1) ss += __shfl_xor(ss, m);
    if (skk == 0) invL[srow] = 1.f / fmaxf(sqrtf(ss), 1e-12f);
    __syncthreads();

    // epilogue scratch carved from Bs0 (all GEMM reads done)
    float* Wt   = (float*)Bs0;           // 16*272 floats
    float* redS = Wt + 16 * 272;         // 16*64
    float* redL = redS + 16 * 64;        // 16*64
    float* rowT = redL + 16 * 64;        // 64
    float* rowL = rowT + 64;             // 64

    // ---- exp (|cos|<=1: no max-sub) + per-wave row sums ----
#pragma unroll
    for (int rt = 0; rt < 4; ++rt)
#pragma unroll
        for (int i = 0; i < 4; ++i) {
            const float inv = invL[rt * 16 + 4 * g + i];
            float s = 0.f;
#pragma unroll
            for (int ct = 0; ct < 4; ++ct) {
                const float e = __expf(acc[rt][ct][i] * inv);
                acc[rt][ct][i] = e;
                s += e;
            }
#pragma unroll
            for (int m = 1; m < 16; m <<= 1) s += __shfl_xor(s, m);
            if (ml == 0) redS[w * 64 + rt * 16 + 4 * g + i] = s;
        }
    __syncthreads();
    if (tid < 64) {
        float t = redS[tid];
#pragma unroll
        for (int ww = 1; ww < 16; ++ww) t += redS[ww * 64 + tid];
        rowT[tid] = 1.f / t;
    }
    __syncthreads();

    // ---- softmax weight, hard-shrink, per-wave row L1 ----
#pragma unroll
    for (int rt = 0; rt < 4; ++rt)
#pragma unroll
        for (int i = 0; i < 4; ++i) {
            const float tinv = rowT[rt * 16 + 4 * g + i];
            float l1 = 0.f;
#pragma unroll
            for (int ct = 0; ct < 4; ++ct) {
                const float wv = acc[rt][ct][i] * tinv;
                const float d = wv - 0.0025f;
                const float v = (d > 0.f) ? (d * wv / (d + 1e-12f)) : 0.f;
                acc[rt][ct][i] = v;
                l1 += v;
            }
#pragma unroll
            for (int m = 1; m < 16; m <<= 1) l1 += __shfl_xor(l1, m);
            if (ml == 0) redL[w * 64 + rt * 16 + 4 * g + i] = l1;
        }
    __syncthreads();
    if (tid < 64) {
        float t = redL[tid];
#pragma unroll
        for (int ww = 1; ww < 16; ++ww) t += redL[ww * 64 + tid];
        rowL[tid] = 1.f / fmaxf(t, 1e-12f);
        rowflag[tid] = (t > 0.f) ? 1 : 0;
        if (t > 0.f) *anyflag = 1;
    }
    __syncthreads();

    // ---- W store via per-wave LDS transpose -> 256B contiguous runs ----
    float* wst = Wt + w * 272;           // 4 x 68 (16B-aligned stride)
#pragma unroll
    for (int rt = 0; rt < 4; ++rt)
#pragma unroll
        for (int i = 0; i < 4; ++i) {
            const float il = rowL[rt * 16 + 4 * g + i];
#pragma unroll
            for (int ct = 0; ct < 4; ++ct)
                wst[g * 68 + ct * 16 + ml] = acc[rt][ct][i] * il;
            // same-wave LDS RAW: compiler inserts lgkmcnt wait
            const f32x4 o = *(const f32x4*)&wst[(lane >> 4) * 68 + (lane & 15) * 4];
            const int row = rt * 16 + (lane >> 4) * 4 + i;
            __builtin_nontemporal_store(
                o, (f32x4*)(out_w + (size_t)(row0 + row) * 1024 + w * 64 + (lane & 15) * 4));
        }

    // ---- zero the mf half ----
    f32x4* dstz = (f32x4*)(out_cat + (size_t)(row0 + srow) * (2 * C));
    const f32x4 z4 = {0.f, 0.f, 0.f, 0.f};
#pragma unroll
    for (int x = 0; x < C / 64; ++x)
        __builtin_nontemporal_store(z4, &dstz[skk + 16 * x]);
    __threadfence();
    __syncthreads();

    // ---- mf fixup: only rows surviving the shrink (essentially never) ----
    if (*anyflag != 0) {
        constexpr int CC = C / 64;
#pragma unroll
        for (int rr = 0; rr < 4; ++rr) {
            const int row = w * 4 + rr;
            if (!rowflag[row]) continue;
            float* dst = out_cat + (size_t)(row0 + row) * (2 * C);
            float mfacc[CC];
#pragma unroll
            for (int cc = 0; cc < CC; ++cc) mfacc[cc] = 0.f;
            const float* wrow = out_w + (size_t)(row0 + row) * 1024;
            for (int jb = 0; jb < 1024; jb += 64) {
                const float wv = wrow[jb + lane];
                unsigned long long msk = __ballot(wv != 0.f);
                while (msk) {
                    const int j = __builtin_ctzll(msk);
                    msk &= msk - 1;
                    const float val = __shfl(wv, j);
                    const float* mrow = memv + (size_t)(jb + j) * C;
#pragma unroll
                    for (int cc = 0; cc < CC; ++cc)
                        mfacc[cc] += val * mrow[cc * 64 + lane];
                }
            }
#pragma unroll
            for (int cc = 0; cc < CC; ++cc) dst[cc * 64 + lane] = mfacc[cc];
        }
    }
}

__global__ __launch_bounds__(1024, 4) void fused_all(
        const float* f0, const float* m0, const short* n0, float* o0, float* w0,
        const float* f1, const float* m1, const short* n1, float* o1, float* w1,
        const float* f2, const float* m2, const short* n2, float* o2, float* w2) {
    __shared__ short Bs[2][32768];       // 2 x 64 KB B tiles
    __shared__ short As[2][2048];        // 2 x 4 KB A tiles
    __shared__ float invL[64];
    __shared__ int rowflag[64];
    __shared__ int anyflag;

    const int bid = blockIdx.x;
    if (bid < 256)
        unit_body<1024>(f2, m2, n2, o2, w2, bid,
                        Bs[0], Bs[1], As[0], As[1], invL, rowflag, &anyflag);
    else if (bid < 512)
        unit_body<512>(f1, m1, n1, o1, w1, bid - 256,
                       Bs[0], Bs[1], As[0], As[1], invL, rowflag, &anyflag);
    else
        unit_body<256>(f0, m0, n0, o0, w0, bid - 512,
                       Bs[0], Bs[1], As[0], As[1], invL, rowflag, &anyflag);
}

extern "C" void kernel_launch(void* const* d_in, const int* in_sizes, int n_in,
                              void* d_out, int out_size, void* d_ws, size_t ws_size,
                              hipStream_t stream) {
    const float* feat[3] = {nullptr, nullptr, nullptr};
    const float* memp[3] = {nullptr, nullptr, nullptr};
    for (int i = 0; i < n_in && i < 6; ++i) {
        const int s = in_sizes[i];
        const float* p = (const float*)d_in[i];
        if (s == 16384 * 256) feat[0] = p;
        else if (s == 16384 * 512) feat[1] = p;
        else if (s == 16384 * 1024) feat[2] = p;
        else if (s == 1024 * 256) memp[0] = p;
        else if (s == 1024 * 512) memp[1] = p;
        else if (s == 1024 * 1024) memp[2] = p;
    }
    float* out = (float*)d_out;
    short* nm0 = (short*)d_ws;
    short* nm1 = nm0 + 1024 * 256;
    short* nm2 = nm1 + 1024 * 512;

    // output layout (floats): out0 | out1 | out2 | w0 | w1 | w2
    const size_t O0 = 0;
    const size_t O1 = (size_t)16384 * 512;
    const size_t O2 = O1 + (size_t)16384 * 1024;
    const size_t W0 = O2 + (size_t)16384 * 2048;
    const size_t W1 = W0 + (size_t)16384 * 1024;
    const size_t W2 = W1 + (size_t)16384 * 1024;

    prep_all<<<192, 256, 0, stream>>>(memp[0], nm0, memp[1], nm1, memp[2], nm2);

    fused_all<<<768, 1024, 0, stream>>>(
        feat[0], memp[0], nm0, out + O0, out + W0,
        feat[1], memp[1], nm1, out + O1, out + W1,
        feat[2], memp[2], nm2, out + O2, out + W2);
}

// Round 10
// 200.104 us; speedup vs baseline: 3.1065x; 3.1065x over previous
//
#include <hip/hip_runtime.h>
#include <stdint.h>

typedef float f32x4 __attribute__((ext_vector_type(4)));
typedef short s16x8 __attribute__((ext_vector_type(8)));
typedef short s16x4 __attribute__((ext_vector_type(4)));

static constexpr int NR = 16384;

__device__ __forceinline__ unsigned short f2bf(float f) {
    uint32_t u = __float_as_uint(f);
    u += 0x7FFFu + ((u >> 16) & 1u);   // round-to-nearest-even
    return (unsigned short)(u >> 16);
}

// ---------- prep: normalize mem rows, emit MFMA-fragment-packed bf16 ----------
// packed frag (ct16,kb): 512 shorts at (ct16*(C/32)+kb)*512;
// short lane*8+j = B[col=ct16*16+(lane&15)][k=kb*32+(lane>>4)*8+j]
template<int C>
__device__ __forceinline__ void prep_body(const float* __restrict__ mp,
                                          short* __restrict__ nmp,
                                          int ct, short* stage) {
    const int tid = threadIdx.x;       // 256 threads
    const int row = tid >> 4;          // 0..15 (B column)
    const int c4  = tid & 15;
    constexpr int IT = C / 64;
    const f32x4* src = (const f32x4*)(mp + (size_t)(ct * 16 + row) * C);
    f32x4 vals[IT];
    float ss = 0.f;
#pragma unroll
    for (int i = 0; i < IT; ++i) {
        f32x4 v = src[c4 + 16 * i];
        vals[i] = v;
        ss += v.x * v.x + v.y * v.y + v.z * v.z + v.w * v.w;
    }
#pragma unroll
    for (int m = 1; m < 16; m <<= 1) ss += __shfl_xor(ss, m);
    const float inv = 1.f / fmaxf(sqrtf(ss), 1e-12f);
#pragma unroll
    for (int i = 0; i < IT; ++i) {
        f32x4 v = vals[i];
        s16x4 o;
        o[0] = (short)f2bf(v.x * inv);
        o[1] = (short)f2bf(v.y * inv);
        o[2] = (short)f2bf(v.z * inv);
        o[3] = (short)f2bf(v.w * inv);
        *(s16x4*)&stage[row * C + (c4 + 16 * i) * 4] = o;
    }
    __syncthreads();
    const int lane = tid & 63;
    const int wv = tid >> 6;
    constexpr int NKB = C / 32;
#pragma unroll
    for (int j = 0; j < NKB / 4; ++j) {
        const int kb = j * 4 + wv;
        const s16x8 v = *(const s16x8*)&stage[(lane & 15) * C + kb * 32 + (lane >> 4) * 8];
        *(s16x8*)&nmp[((size_t)ct * NKB + kb) * 512 + lane * 8] = v;
    }
}

__global__ __launch_bounds__(256) void prep_all(const float* m0, short* n0,
                                                const float* m1, short* n1,
                                                const float* m2, short* n2) {
    __shared__ short stage[16 * 1024];
    const int bid = blockIdx.x;
    if (bid < 64) prep_body<256>(m0, n0, bid, stage);
    else if (bid < 128) prep_body<512>(m1, n1, bid - 64, stage);
    else prep_body<1024>(m2, n2, bid - 128, stage);
}

// ---------- copy kernel: pure streaming (f-copy, mf zeros, invn) ----------
template<int C>
__device__ __forceinline__ void copy_body(const float* __restrict__ feat,
                                          float* __restrict__ out_cat,
                                          float* __restrict__ inv_arr, int tt) {
    const int tid = threadIdx.x;        // 256
    const int row = tid >> 4;           // 0..15
    const int c4  = tid & 15;
    constexpr int IT = C / 64;
    const f32x4* src = (const f32x4*)(feat + (size_t)(tt * 16 + row) * C);
    f32x4* dstf = (f32x4*)(out_cat + (size_t)(tt * 16 + row) * (2 * C) + C);
    f32x4* dstz = (f32x4*)(out_cat + (size_t)(tt * 16 + row) * (2 * C));
    const f32x4 z4 = {0.f, 0.f, 0.f, 0.f};
    float ss = 0.f;
#pragma unroll
    for (int i = 0; i < IT; ++i) {
        const int idx = c4 + 16 * i;
        f32x4 v = __builtin_nontemporal_load(&src[idx]);
        __builtin_nontemporal_store(v, &dstf[idx]);
        __builtin_nontemporal_store(z4, &dstz[idx]);
        ss += v.x * v.x + v.y * v.y + v.z * v.z + v.w * v.w;
    }
#pragma unroll
    for (int m = 1; m < 16; m <<= 1) ss += __shfl_xor(ss, m);
    if (c4 == 0) inv_arr[tt * 16 + row] = 1.f / fmaxf(sqrtf(ss), 1e-12f);
}

__global__ __launch_bounds__(256) void copy_all(const float* f0, float* o0,
                                                const float* f1, float* o1,
                                                const float* f2, float* o2,
                                                float* invA) {
    const int bid = blockIdx.x;
    if (bid < 1024) copy_body<1024>(f2, o2, invA + 2 * NR, bid);
    else if (bid < 2048) copy_body<512>(f1, o1, invA + NR, bid - 1024);
    else copy_body<256>(f0, o0, invA, bid - 2048);
}

// ---------- GEMM kernel: BM=64 x BN=1024, 16 waves, lgkm-only barriers ----------
// A: f re-read from L3, converted, LDS dbuf (XOR-swizzled). B: packed frags
// from L2, register-prefetched ACROSS the barrier. No stores in the K-loop.
template<int C>
__device__ __forceinline__ void gemm_body(const float* __restrict__ feat,
                                          const float* __restrict__ memv,
                                          const short* __restrict__ nm,
                                          const float* __restrict__ inv_arr,
                                          float* __restrict__ out_cat,
                                          float* __restrict__ out_w,
                                          int tile,
                                          short* __restrict__ As,
                                          float (*__restrict__ red)[64],
                                          float* __restrict__ rowT,
                                          float* __restrict__ rowL,
                                          float* __restrict__ invL,
                                          int* __restrict__ rowflag,
                                          int* __restrict__ anyflag) {
    constexpr int NKB = C / 32;          // MFMA K-steps
    constexpr int NCH = C / 64;          // LDS chunks (64 k each)
    const int tid  = threadIdx.x;        // 0..1023
    const int w    = tid >> 6;           // wave 0..15
    const int lane = tid & 63;
    const int g    = lane >> 4;
    const int ml   = lane & 15;
    const int swz  = ml & 7;
    const int row0 = tile * 64;

    // fill role: thread -> (row 0..63, f32x4 slot 0..15 within 64-float chunk)
    const int frow = tid >> 4;
    const int fk4  = tid & 15;
    const float* fsrc = feat + (size_t)(row0 + frow) * C + fk4 * 4;
    const int ldsW = frow * 64 + (((fk4 >> 1) ^ (frow & 7)) << 3) + (fk4 & 1) * 4;
    // B: wave w owns col-tiles w*4 .. w*4+3 (cols w*64..w*64+63)
    const short* nbB = nm + (size_t)(w * 4) * NKB * 512 + lane * 8;

    if (tid == 0) *anyflag = 0;
    if (tid < 64) invL[tid] = inv_arr[row0 + tid];

    f32x4 acc[4][4];
#pragma unroll
    for (int r = 0; r < 4; ++r)
#pragma unroll
        for (int ct = 0; ct < 4; ++ct)
            acc[r][ct] = (f32x4){0.f, 0.f, 0.f, 0.f};

    // ---- prologue: fill chunk0, prefetch chunk1 f, load B(kb=0) ----
    {
        const f32x4 v = *(const f32x4*)fsrc;
        s16x4 o;
        o[0] = (short)f2bf(v.x); o[1] = (short)f2bf(v.y);
        o[2] = (short)f2bf(v.z); o[3] = (short)f2bf(v.w);
        *(s16x4*)&As[ldsW] = o;
    }
    f32x4 fnxt;
    if (NCH > 1) fnxt = *(const f32x4*)(fsrc + 64);
    s16x8 bc[4];
#pragma unroll
    for (int ct = 0; ct < 4; ++ct)
        bc[ct] = *(const s16x8*)(nbB + (size_t)ct * NKB * 512);
    asm volatile("s_waitcnt lgkmcnt(0)" ::: "memory");
    __builtin_amdgcn_s_barrier();
    asm volatile("" ::: "memory");

    // ---- K loop ----
    for (int kb = 0; kb < NKB; ++kb) {
        const int chunk = kb >> 1;
        if ((kb & 1) == 0 && chunk + 1 < NCH) {
            // fill next chunk's LDS buffer from the prefetched registers
            s16x4 o;
            o[0] = (short)f2bf(fnxt.x); o[1] = (short)f2bf(fnxt.y);
            o[2] = (short)f2bf(fnxt.z); o[3] = (short)f2bf(fnxt.w);
            *(s16x4*)&As[((chunk + 1) & 1) * 4096 + ldsW] = o;
            if (chunk + 2 < NCH)
                fnxt = *(const f32x4*)(fsrc + (size_t)(chunk + 2) * 64);
        }
        // prefetch next kb's B frags (stay in flight across the barrier)
        s16x8 bn[4];
        const bool more = (kb + 1 < NKB);
        if (more) {
#pragma unroll
            for (int ct = 0; ct < 4; ++ct)
                bn[ct] = *(const s16x8*)(nbB + ((size_t)ct * NKB + kb + 1) * 512);
        }
        // A fragments from LDS
        const short* Ab = &As[(chunk & 1) * 4096];
        const int gr = ((kb & 1) << 2) | g;
        s16x8 a[4];
#pragma unroll
        for (int r = 0; r < 4; ++r)
            a[r] = *(const s16x8*)&Ab[(r * 16 + ml) * 64 + ((gr ^ swz) << 3)];
        __builtin_amdgcn_s_setprio(1);
#pragma unroll
        for (int r = 0; r < 4; ++r)
#pragma unroll
            for (int ct = 0; ct < 4; ++ct)
                acc[r][ct] = __builtin_amdgcn_mfma_f32_16x16x32_bf16(a[r], bc[ct], acc[r][ct], 0, 0, 0);
        __builtin_amdgcn_s_setprio(0);
        if (more) {
#pragma unroll
            for (int ct = 0; ct < 4; ++ct) bc[ct] = bn[ct];
        }
        if ((kb & 1) == 1 && kb + 1 < NKB) {
            asm volatile("s_waitcnt lgkmcnt(0)" ::: "memory");
            __builtin_amdgcn_s_barrier();
            asm volatile("" ::: "memory");
        }
    }
    __syncthreads();

    // C/D: global row = r*16 + 4*g + i, global col = (w*4+ct)*16 + ml
    float IL[4][4];

    // ---- exp (|cos|<=1: no max-sub) + row sums ----
#pragma unroll
    for (int r = 0; r < 4; ++r)
#pragma unroll
        for (int i = 0; i < 4; ++i) {
            const float inv = invL[r * 16 + 4 * g + i];
            float s = 0.f;
#pragma unroll
            for (int ct = 0; ct < 4; ++ct) {
                const float e = __expf(acc[r][ct][i] * inv);
                acc[r][ct][i] = e;
                s += e;
            }
#pragma unroll
            for (int m = 1; m < 16; m <<= 1) s += __shfl_xor(s, m);
            if (ml == 0) red[w][r * 16 + 4 * g + i] = s;
        }
    __syncthreads();
    if (tid < 64) {
        float t = red[0][tid];
#pragma unroll
        for (int ww = 1; ww < 16; ++ww) t += red[ww][tid];
        rowT[tid] = 1.f / t;
    }
    __syncthreads();

    // ---- softmax weight, hard-shrink, row L1 ----
#pragma unroll
    for (int r = 0; r < 4; ++r)
#pragma unroll
        for (int i = 0; i < 4; ++i) {
            const float tinv = rowT[r * 16 + 4 * g + i];
            float l1 = 0.f;
#pragma unroll
            for (int ct = 0; ct < 4; ++ct) {
                const float wv = acc[r][ct][i] * tinv;
                const float d = wv - 0.0025f;
                const float v = (d > 0.f) ? (d * wv / (d + 1e-12f)) : 0.f;
                acc[r][ct][i] = v;
                l1 += v;
            }
#pragma unroll
            for (int m = 1; m < 16; m <<= 1) l1 += __shfl_xor(l1, m);
            if (ml == 0) red[w][r * 16 + 4 * g + i] = l1;
        }
    __syncthreads();
    if (tid < 64) {
        float t = red[0][tid];
#pragma unroll
        for (int ww = 1; ww < 16; ++ww) t += red[ww][tid];
        rowL[tid] = 1.f / fmaxf(t, 1e-12f);
        rowflag[tid] = (t > 0.f) ? 1 : 0;
        if (t > 0.f) *anyflag = 1;
    }
    __syncthreads();

    // ---- store W (normal cached stores; L2 assembles full lines) ----
#pragma unroll
    for (int r = 0; r < 4; ++r)
#pragma unroll
        for (int i = 0; i < 4; ++i) {
            const float il = rowL[r * 16 + 4 * g + i];
            float* orow = out_w + (size_t)(row0 + r * 16 + 4 * g + i) * 1024;
#pragma unroll
            for (int ct = 0; ct < 4; ++ct)
                orow[(w * 4 + ct) * 16 + ml] = acc[r][ct][i] * il;
        }
    __threadfence_block();
    __syncthreads();

    // ---- mf fixup: only rows surviving the shrink (zeros pre-written by copy) ----
    if (*anyflag != 0) {
        constexpr int CC = C / 64;
#pragma unroll
        for (int rr = 0; rr < 4; ++rr) {
            const int row = w * 4 + rr;
            if (!rowflag[row]) continue;
            float* dst = out_cat + (size_t)(row0 + row) * (2 * C);
            float mfacc[CC];
#pragma unroll
            for (int cc = 0; cc < CC; ++cc) mfacc[cc] = 0.f;
            const float* wrow = out_w + (size_t)(row0 + row) * 1024;
            for (int jb = 0; jb < 1024; jb += 64) {
                const float wv = wrow[jb + lane];
                unsigned long long msk = __ballot(wv != 0.f);
                while (msk) {
                    const int j = __builtin_ctzll(msk);
                    msk &= msk - 1;
                    const float val = __shfl(wv, j);
                    const float* mrow = memv + (size_t)(jb + j) * C;
#pragma unroll
                    for (int cc = 0; cc < CC; ++cc)
                        mfacc[cc] += val * mrow[cc * 64 + lane];
                }
            }
#pragma unroll
            for (int cc = 0; cc < CC; ++cc) dst[cc * 64 + lane] = mfacc[cc];
        }
    }
}

// unit-sorted: unit2 first (nm2 L2-hot), then unit1, unit0
__global__ __launch_bounds__(1024) void gemm_all(
        const float* f0, const float* m0, const short* n0, float* o0, float* w0,
        const float* f1, const float* m1, const short* n1, float* o1, float* w1,
        const float* f2, const float* m2, const short* n2, float* o2, float* w2,
        const float* invA) {
    __shared__ short As[2 * 4096];       // 2 x 8 KB A chunks
    __shared__ float red[16][64];
    __shared__ float rowT[64];
    __shared__ float rowL[64];
    __shared__ float invL[64];
    __shared__ int rowflag[64];
    __shared__ int anyflag;

    const int bid = blockIdx.x;
    if (bid < 256)
        gemm_body<1024>(f2, m2, n2, invA + 2 * NR, o2, w2, bid,
                        As, red, rowT, rowL, invL, rowflag, &anyflag);
    else if (bid < 512)
        gemm_body<512>(f1, m1, n1, invA + NR, o1, w1, bid - 256,
                       As, red, rowT, rowL, invL, rowflag, &anyflag);
    else
        gemm_body<256>(f0, m0, n0, invA, o0, w0, bid - 512,
                       As, red, rowT, rowL, invL, rowflag, &anyflag);
}

extern "C" void kernel_launch(void* const* d_in, const int* in_sizes, int n_in,
                              void* d_out, int out_size, void* d_ws, size_t ws_size,
                              hipStream_t stream) {
    const float* feat[3] = {nullptr, nullptr, nullptr};
    const float* memp[3] = {nullptr, nullptr, nullptr};
    for (int i = 0; i < n_in && i < 6; ++i) {
        const int s = in_sizes[i];
        const float* p = (const float*)d_in[i];
        if (s == 16384 * 256) feat[0] = p;
        else if (s == 16384 * 512) feat[1] = p;
        else if (s == 16384 * 1024) feat[2] = p;
        else if (s == 1024 * 256) memp[0] = p;
        else if (s == 1024 * 512) memp[1] = p;
        else if (s == 1024 * 1024) memp[2] = p;
    }
    float* out = (float*)d_out;
    short* nm0 = (short*)d_ws;
    short* nm1 = nm0 + 1024 * 256;
    short* nm2 = nm1 + 1024 * 512;
    float* invA = (float*)(nm2 + 1024 * 1024);   // 3 x 16384 floats

    // output layout (floats): out0 | out1 | out2 | w0 | w1 | w2
    const size_t O0 = 0;
    const size_t O1 = (size_t)16384 * 512;
    const size_t O2 = O1 + (size_t)16384 * 1024;
    const size_t W0 = O2 + (size_t)16384 * 2048;
    const size_t W1 = W0 + (size_t)16384 * 1024;
    const size_t W2 = W1 + (size_t)16384 * 1024;

    prep_all<<<192, 256, 0, stream>>>(memp[0], nm0, memp[1], nm1, memp[2], nm2);

    copy_all<<<3072, 256, 0, stream>>>(feat[0], out + O0,
                                       feat[1], out + O1,
                                       feat[2], out + O2, invA);

    gemm_all<<<768, 1024, 0, stream>>>(
        feat[0], memp[0], nm0, out + O0, out + W0,
        feat[1], memp[1], nm1, out + O1, out + W1,
        feat[2], memp[2], nm2, out + O2, out + W2, invA);
}